// Round 1
// baseline (79.480 us; speedup 1.0000x reference)
//
#include <hip/hip_runtime.h>

// LogSig_var: depth-2 log-signature over 64 segments of ragged paths.
// inp:    (256, 2048, 12) fp32
// length: (256,) int32, 1..2048
// out:    (256, 64, 78) fp32   [12 increments + 66 Levy areas (i<j lex order)]
//
// Per-segment algebra (segments independent, no cumsum needed):
//   inc_i  = Xb_i - Xa_i
//   levy_p = 0.5*( sum_{t=a}^{b-1} [X_i(t)X_j(t+1) - X_j(t)X_i(t+1)]
//                  - (Xa_i*Xb_j - Xa_j*Xb_i) )
//
// Boundary indices tv = round_half_even(1 + j*(Leff-1)/64) computed exactly
// in integer arithmetic (value is a dyadic rational with denominator 64).

#define BATCH 256
#define TLEN 2048
#define DCH 12
#define NSEG 64
#define NPAIR 66          // d*(d-1)/2
#define NCH 78            // 12 + 66

__device__ __forceinline__ int tv_round(int j, int Lf) {
    // round-half-even(1 + j*Lf/64), exact. q = j*Lf <= 64*2047 < 2^17.
    int q = j * Lf;
    int base = 1 + (q >> 6);
    int r = q & 63;
    int up = (r > 32) || (r == 32 && (base & 1));
    return base + up;
}

__global__ __launch_bounds__(256) void logsig_kernel(
        const float* __restrict__ inp,
        const int* __restrict__ length,
        float* __restrict__ out) {
    __shared__ __align__(16) float lds_x[TLEN * DCH];    // 98304 B
    __shared__ __align__(16) float lds_out[NSEG * NCH];  // 19968 B

    const int batch = blockIdx.x;
    const int tid = threadIdx.x;
    const int L = length[batch];

    // ---- stage X[0..L-1] into LDS, coalesced float4 (L*12 = L*3 float4) ----
    {
        const float4* src = (const float4*)(inp + (size_t)batch * TLEN * DCH);
        float4* dst = (float4*)lds_x;
        const int nvec = L * 3;
        for (int i = tid; i < nvec; i += 256) dst[i] = src[i];
    }
    __syncthreads();

    // ---- segment assignment: 4 contiguous lanes per segment ----
    const int lane = tid & 63;
    const int wave = tid >> 6;
    const int seg = wave * 16 + (lane >> 2);
    const int q4 = lane & 3;

    const bool expand = (L < NSEG + 1);
    const int k = expand ? (NSEG / L + 1) : 1;
    const int Leff = expand ? k * L : L;
    const int Lf = Leff - 1;

    const int a = tv_round(seg, Lf) - 1;
    const int b = tv_round(seg + 1, Lf) - 1;

    float acc[NPAIR];
#pragma unroll
    for (int p = 0; p < NPAIR; ++p) acc[p] = 0.0f;

    for (int t = a + q4; t < b; t += 4) {
        int r0, r1;
        if (expand) {
            r0 = min(t / k, L - 1);
            r1 = min((t + 1) / k, L - 1);
        } else {
            r0 = t;
            r1 = t + 1;
        }
        float x[DCH], y[DCH];
        const float4* px = (const float4*)(lds_x + r0 * DCH);
        const float4* py = (const float4*)(lds_x + r1 * DCH);
#pragma unroll
        for (int v = 0; v < 3; ++v) {
            float4 fx = px[v];
            float4 fy = py[v];
            x[4 * v + 0] = fx.x; x[4 * v + 1] = fx.y;
            x[4 * v + 2] = fx.z; x[4 * v + 3] = fx.w;
            y[4 * v + 0] = fy.x; y[4 * v + 1] = fy.y;
            y[4 * v + 2] = fy.z; y[4 * v + 3] = fy.w;
        }
        int p = 0;
#pragma unroll
        for (int i = 0; i < DCH - 1; ++i)
#pragma unroll
            for (int jj = i + 1; jj < DCH; ++jj) {
                acc[p] += x[i] * y[jj] - x[jj] * y[i];
                ++p;
            }
    }

    // ---- reduce the 4 lanes of each segment (contiguous lanes -> same wave)
#pragma unroll
    for (int p = 0; p < NPAIR; ++p) {
        acc[p] += __shfl_xor(acc[p], 1, 64);
        acc[p] += __shfl_xor(acc[p], 2, 64);
    }

    // ---- writer lane: boundary term + store channels to LDS ----
    if (q4 == 0) {
        int ra, rb;
        if (expand) {
            ra = min(a / k, L - 1);
            rb = min(b / k, L - 1);
        } else {
            ra = a;
            rb = b;
        }
        float xa[DCH], xb[DCH];
#pragma unroll
        for (int i = 0; i < DCH; ++i) {
            xa[i] = lds_x[ra * DCH + i];
            xb[i] = lds_x[rb * DCH + i];
        }
        float* o = lds_out + seg * NCH;
#pragma unroll
        for (int i = 0; i < DCH; ++i) o[i] = xb[i] - xa[i];
        int p = 0;
#pragma unroll
        for (int i = 0; i < DCH - 1; ++i)
#pragma unroll
            for (int jj = i + 1; jj < DCH; ++jj) {
                o[DCH + p] = 0.5f * (acc[p] - (xa[i] * xb[jj] - xa[jj] * xb[i]));
                ++p;
            }
    }
    __syncthreads();

    // ---- coalesced copy-out: 64*78 = 4992 floats = 1248 float4 ----
    {
        float4* od = (float4*)(out + (size_t)batch * NSEG * NCH);
        const float4* os = (const float4*)lds_out;
        for (int i = tid; i < (NSEG * NCH) / 4; i += 256) od[i] = os[i];
    }
}

extern "C" void kernel_launch(void* const* d_in, const int* in_sizes, int n_in,
                              void* d_out, int out_size, void* d_ws, size_t ws_size,
                              hipStream_t stream) {
    const float* inp = (const float*)d_in[0];
    const int* length = (const int*)d_in[1];
    float* out = (float*)d_out;
    logsig_kernel<<<BATCH, 256, 0, stream>>>(inp, length, out);
}

// Round 2
// 75.150 us; speedup vs baseline: 1.0576x; 1.0576x over previous
//
#include <hip/hip_runtime.h>

// LogSig_var: depth-2 log-signature over 64 segments of ragged paths.
// inp:    (256, 2048, 12) fp32
// length: (256,) int32, 1..2048
// out:    (256, 64, 78) fp32   [12 increments + 66 Levy areas (i<j lex order)]
//
// Per-segment algebra (segments independent, no cumsum needed):
//   inc_i  = Xb_i - Xa_i
//   levy_p = 0.5*( sum_{t=a}^{b-1} [X_i(t)X_j(t+1) - X_j(t)X_i(t+1)]
//                  - (Xa_i*Xb_j - Xa_j*Xb_i) )
//
// R1 change: direct-global reads in the compute loop (no LDS staging of X).
// Rationale: staging loop had dynamic trip count -> serialized
// load->waitcnt->ds_write chain at 1 wave/SIMD; and the 98KB LDS tile gave
// 16-way bank conflicts (segment stride for L=2048 is exactly 32 rows, so all
// 16 segments/wave hit identical banks). Rows come from L2/LLC (input is
// 25 MB, just rewritten by the harness restore). LDS now only 20 KB.

#define BATCH 256
#define TLEN 2048
#define DCH 12
#define NSEG 64
#define NPAIR 66          // d*(d-1)/2
#define NCH 78            // 12 + 66

__device__ __forceinline__ int tv_round(int j, int Lf) {
    // round-half-even(1 + j*Lf/64), exact. q = j*Lf <= 64*2047 < 2^17.
    int q = j * Lf;
    int base = 1 + (q >> 6);
    int r = q & 63;
    int up = (r > 32) || (r == 32 && (base & 1));
    return base + up;
}

__device__ __forceinline__ void load_row(const float* __restrict__ X, int r,
                                         float* __restrict__ v) {
    const float4* p = (const float4*)(X + r * DCH);
    float4 f0 = p[0], f1 = p[1], f2 = p[2];
    v[0] = f0.x; v[1] = f0.y; v[2]  = f0.z; v[3]  = f0.w;
    v[4] = f1.x; v[5] = f1.y; v[6]  = f1.z; v[7]  = f1.w;
    v[8] = f2.x; v[9] = f2.y; v[10] = f2.z; v[11] = f2.w;
}

__global__ __launch_bounds__(256) void logsig_kernel(
        const float* __restrict__ inp,
        const int* __restrict__ length,
        float* __restrict__ out) {
    __shared__ __align__(16) float lds_out[NSEG * NCH];  // 19968 B

    const int batch = blockIdx.x;
    const int tid = threadIdx.x;
    const int L = length[batch];

    const float* __restrict__ X = inp + (size_t)batch * TLEN * DCH;

    // ---- segment assignment: 4 contiguous lanes per segment ----
    const int lane = tid & 63;
    const int wave = tid >> 6;
    const int seg = wave * 16 + (lane >> 2);
    const int q4 = lane & 3;

    const bool expand = (L < NSEG + 1);
    const int k = expand ? (NSEG / L + 1) : 1;
    const int Leff = expand ? k * L : L;
    const int Lf = Leff - 1;

    const int a = tv_round(seg, Lf) - 1;
    const int b = tv_round(seg + 1, Lf) - 1;

    float acc[NPAIR];
#pragma unroll
    for (int p = 0; p < NPAIR; ++p) acc[p] = 0.0f;

    for (int t = a + q4; t < b; t += 4) {
        int r0, r1;
        if (expand) {
            r0 = min(t / k, L - 1);
            r1 = min((t + 1) / k, L - 1);
        } else {
            r0 = t;
            r1 = t + 1;
        }
        float x[DCH], y[DCH];
        load_row(X, r0, x);
        load_row(X, r1, y);
        int p = 0;
#pragma unroll
        for (int i = 0; i < DCH - 1; ++i)
#pragma unroll
            for (int jj = i + 1; jj < DCH; ++jj) {
                acc[p] = fmaf(x[i], y[jj], acc[p]);
                acc[p] = fmaf(-x[jj], y[i], acc[p]);
                ++p;
            }
    }

    // ---- reduce the 4 lanes of each segment (contiguous lanes -> same wave)
#pragma unroll
    for (int p = 0; p < NPAIR; ++p) {
        acc[p] += __shfl_xor(acc[p], 1, 64);
        acc[p] += __shfl_xor(acc[p], 2, 64);
    }

    // ---- writer lane: boundary term + store channels to LDS ----
    if (q4 == 0) {
        int ra, rb;
        if (expand) {
            ra = min(a / k, L - 1);
            rb = min(b / k, L - 1);
        } else {
            ra = a;
            rb = b;
        }
        float xa[DCH], xb[DCH];
        load_row(X, ra, xa);
        load_row(X, rb, xb);
        float* o = lds_out + seg * NCH;
#pragma unroll
        for (int i = 0; i < DCH; ++i) o[i] = xb[i] - xa[i];
        int p = 0;
#pragma unroll
        for (int i = 0; i < DCH - 1; ++i)
#pragma unroll
            for (int jj = i + 1; jj < DCH; ++jj) {
                o[DCH + p] = 0.5f * (acc[p] - (xa[i] * xb[jj] - xa[jj] * xb[i]));
                ++p;
            }
    }
    __syncthreads();

    // ---- coalesced copy-out: 64*78 = 4992 floats = 1248 float4 ----
    {
        float4* od = (float4*)(out + (size_t)batch * NSEG * NCH);
        const float4* os = (const float4*)lds_out;
        for (int i = tid; i < (NSEG * NCH) / 4; i += 256) od[i] = os[i];
    }
}

extern "C" void kernel_launch(void* const* d_in, const int* in_sizes, int n_in,
                              void* d_out, int out_size, void* d_ws, size_t ws_size,
                              hipStream_t stream) {
    const float* inp = (const float*)d_in[0];
    const int* length = (const int*)d_in[1];
    float* out = (float*)d_out;
    logsig_kernel<<<BATCH, 256, 0, stream>>>(inp, length, out);
}